// Round 8
// baseline (222.983 us; speedup 1.0000x reference)
//
#include <hip/hip_runtime.h>
#include <hip/hip_bf16.h>

#define IN_F   1024
#define OUT_F  1024
#define NCH    9
#define KDIM   9216               // 9 channels * 1024 features, channel-major: k = c*1024 + f
#define BATCH  8192

// ---- GEMM: 256x256 tile, BK=32, 8 waves (2M x 4N), 4-slot LDS ring, K-split x2 ----
#define BM 256
#define BN 256
#define BK 32
#define KHALF 4608
#define NTK (KHALF / BK)          // 144 K-tiles per half
#define SLOT 16384                // u16 per ring slot: A 8192 | B 8192  (32 KiB)

typedef __attribute__((ext_vector_type(4)))  float  f32x4;
typedef __attribute__((ext_vector_type(16))) float  f32x16;
typedef __attribute__((ext_vector_type(8)))  __bf16 bf16x8;

typedef __attribute__((address_space(3))) unsigned short       lds_u16;
typedef const __attribute__((address_space(1))) unsigned short glb_u16;

__device__ inline unsigned short f2bf(float f) {
    union { float f; unsigned int u; } v; v.f = f;
    unsigned int u = v.u;
    unsigned int r = (u + 0x7FFFu + ((u >> 16) & 1u)) >> 16;   // RNE
    return (unsigned short)r;
}

// ---------------------------------------------------------------------------
// Kernel 1: combined weights, channel-major: W[o][c*1024 + f]
// ---------------------------------------------------------------------------
__global__ void wgt_kernel(const float* __restrict__ bw,
                           const float* __restrict__ sw,
                           const float* __restrict__ sc,
                           unsigned short* __restrict__ W) {
    int idx = blockIdx.x * blockDim.x + threadIdx.x;     // o*1024 + f
    if (idx >= OUT_F * IN_F) return;
    int o = idx >> 10, f = idx & 1023;
    float scale = sc[idx];
    const float4* swp = (const float4*)(sw + (size_t)idx * 8);
    float4 w0 = swp[0], w1 = swp[1];
    unsigned short* Wb = W + (size_t)o * KDIM + f;
    Wb[0 * 1024] = f2bf(w0.x * scale);
    Wb[1 * 1024] = f2bf(w0.y * scale);
    Wb[2 * 1024] = f2bf(w0.z * scale);
    Wb[3 * 1024] = f2bf(w0.w * scale);
    Wb[4 * 1024] = f2bf(w1.x * scale);
    Wb[5 * 1024] = f2bf(w1.y * scale);
    Wb[6 * 1024] = f2bf(w1.z * scale);
    Wb[7 * 1024] = f2bf(w1.w * scale);
    Wb[8 * 1024] = f2bf(bw[idx]);
}

// ---------------------------------------------------------------------------
// Kernel 2: activations, channel-major: A[r][c*1024 + f]
// 8 features/thread: 2x float4 loads, 9 x dwordx4 (16B) coalesced stores.
// ---------------------------------------------------------------------------
__global__ void act_kernel(const float* __restrict__ x,
                           unsigned short* __restrict__ A) {
    int idx = blockIdx.x * blockDim.x + threadIdx.x;     // r*128 + f8
    if (idx >= BATCH * 128) return;
    const float4* xp = (const float4*)(x + (size_t)idx * 8);
    float4 x0 = xp[0], x1 = xp[1];
    float xs[8] = {x0.x, x0.y, x0.z, x0.w, x1.x, x1.y, x1.z, x1.w};

    unsigned short vals[8][9];
#pragma unroll
    for (int e = 0; e < 8; ++e) {
        float v  = xs[e];
        float s  = v / (1.0f + __expf(-v));              // silu

        float t  = (v + 2.2f) * 2.5f;                    // (x - g0)/h
        float jf = floorf(t);
        int   j  = (int)jf;
        float u  = t - jf;
        float u2 = u * u, u3 = u2 * u;
        float p0 = u3 * (1.0f / 6.0f);
        float p1 = (-3.0f * u3 + 3.0f * u2 + 3.0f * u + 1.0f) * (1.0f / 6.0f);
        float p2 = (3.0f * u3 - 6.0f * u2 + 4.0f) * (1.0f / 6.0f);
        float om = 1.0f - u;
        float p3 = om * om * om * (1.0f / 6.0f);
        bool valid = (v >= -2.2f) && (v < 2.2f);

#pragma unroll
        for (int c = 0; c < 8; ++c) {
            int p = j - c;
            float bv = 0.0f;
            if (valid)
                bv = (p == 0) ? p0 : (p == 1) ? p1 : (p == 2) ? p2 : (p == 3) ? p3 : 0.0f;
            vals[e][c] = f2bf(bv);
        }
        vals[e][8] = f2bf(s);
    }

    int r = idx >> 7, f8 = idx & 127;
    unsigned short* base = A + (size_t)r * KDIM + f8 * 8;
#pragma unroll
    for (int c = 0; c < 9; ++c) {
        uint4 pk;
        pk.x = (unsigned int)vals[0][c] | ((unsigned int)vals[1][c] << 16);
        pk.y = (unsigned int)vals[2][c] | ((unsigned int)vals[3][c] << 16);
        pk.z = (unsigned int)vals[4][c] | ((unsigned int)vals[5][c] << 16);
        pk.w = (unsigned int)vals[6][c] | ((unsigned int)vals[7][c] << 16);
        *(uint4*)(base + (size_t)c * 1024) = pk;
    }
}

// ---------------------------------------------------------------------------
// Kernel 3: K-split ring GEMM, 32x32x16 MFMA (2382 TF rate vs 2075 for
// 16x16x32), ONE barrier per K-tile, 4-slot ring, counted vmcnt(8).
// Fragment layout 32x32x16: A lane l: row=l&31, k=(l>>5)*8; B same on W-rows.
// Swizzle (both sides): phys chunk = logical ^ ((row>>1)&3) — 8 lanes per
// (parity,chunk) slot x 8 slots = minimum depth, conflict-free.
// C/D: col=lane&31, row=(reg&3)+8*(reg>>2)+4*(lane>>5)  [m74/m101 verified].
// ---------------------------------------------------------------------------
#define DECLS(q) \
    const int ci##q = (q) * 512 + tid; \
    const int lo##q = ci##q << 3; \
    const int rr##q = ci##q >> 2; \
    const int cl##q = (((ci##q & 3) ^ ((rr##q >> 1) & 3)) << 3); \
    const unsigned short* srcA##q = Ap + (size_t)(m0 + rr##q) * KDIM + kbase + cl##q; \
    const unsigned short* srcB##q = Wp + (size_t)(n0 + rr##q) * KDIM + kbase + cl##q;

#define STAGE_A(q, ns) do { \
    __builtin_amdgcn_global_load_lds((glb_u16*)srcA##q, (lds_u16*)(ns) + lo##q, 16, 0, 0); \
    srcA##q += BK; } while (0)

#define STAGE_B(q, ns) do { \
    __builtin_amdgcn_global_load_lds((glb_u16*)srcB##q, (lds_u16*)(ns) + 8192 + lo##q, 16, 0, 0); \
    srcB##q += BK; } while (0)

// 32x32 fragment reads: row = base + l31, chunk = kk*2 + l5, phys ^= (l31>>1)&3
#define RDA32(mi, kf) (*(const bf16x8*)&sA[(rowa + (mi) * 32) * BK + (kf)])
#define RDB32(ni, kf) (*(const bf16x8*)&sB[(rowb + (ni) * 32) * BK + (kf)])

#define MFMA32(av, bv, cv) __builtin_amdgcn_mfma_f32_32x32x16_bf16(av, bv, cv, 0, 0, 0)

#define MMROW(mi) do { \
    bf16x8 a0 = RDA32(mi, kf0), a1 = RDA32(mi, kf1); \
    acc[mi][0] = MFMA32(a0, b00, acc[mi][0]); \
    acc[mi][0] = MFMA32(a1, b01, acc[mi][0]); \
    acc[mi][1] = MFMA32(a0, b10, acc[mi][1]); \
    acc[mi][1] = MFMA32(a1, b11, acc[mi][1]); \
} while (0)

__global__ __launch_bounds__(512, 2) void gemm_ring(
    const unsigned short* __restrict__ Ap,
    const unsigned short* __restrict__ Wp,
    float* __restrict__ C, float* __restrict__ P, int mode) {
    __shared__ unsigned short lds[4 * SLOT];             // 128 KiB ring

    const int tid  = threadIdx.x;
    const int wave = tid >> 6;
    const int lane = tid & 63;
    const int l31  = lane & 31;
    const int l5   = lane >> 5;
    // read-side swizzle constants (phys chunk = logical ^ ((l31>>1)&3)), in u16
    const int sw3  = (l31 >> 1) & 3;
    const int kf0  = ((0 * 2 + l5) ^ sw3) << 3;          // kk=0 chunk
    const int kf1  = ((1 * 2 + l5) ^ sw3) << 3;          // kk=1 chunk

    // bid -> (kb, m, n): XCD x = bid&7 fixed (kb = bit2, mgroup = bits 0-1);
    // within an XCD: 8 m-panels x 4 n -> A,B panels L2-resident per XCD.
    const int bid  = blockIdx.x;
    const int mg   = bid & 3;
    const int kb   = (bid >> 2) & 1;
    const int j    = bid >> 3;
    const int m0   = (mg * 8 + (j >> 2)) * BM;
    const int n0   = (j & 3) * BN;
    const int kbase = kb * KHALF;

    const int wr = wave >> 2;                            // 0..1 (M)
    const int wc = wave & 3;                             // 0..3 (N)
    const int rowa = wr * 128 + l31;                     // + mi*32
    const int rowb = wc * 64 + l31;                      // + ni*32

    f32x16 acc[4][2];
#pragma unroll
    for (int i = 0; i < 4; ++i)
#pragma unroll
        for (int jn = 0; jn < 2; ++jn) acc[i][jn] = (f32x16)(0.0f);

    DECLS(0) DECLS(1)

    // prologue: stage tiles 0,1,2 into slots 0,1,2 (12 loads/thread)
    {
        unsigned short* ns = lds;
        STAGE_A(0, ns); STAGE_A(1, ns); STAGE_B(0, ns); STAGE_B(1, ns);
    }
    {
        unsigned short* ns = lds + SLOT;
        STAGE_A(0, ns); STAGE_A(1, ns); STAGE_B(0, ns); STAGE_B(1, ns);
    }
    {
        unsigned short* ns = lds + 2 * SLOT;
        STAGE_A(0, ns); STAGE_A(1, ns); STAGE_B(0, ns); STAGE_B(1, ns);
    }
    asm volatile("s_waitcnt vmcnt(8)" ::: "memory");     // tile 0 landed
    __builtin_amdgcn_s_barrier();

#pragma unroll 4
    for (int t = 0; t < NTK; ++t) {
        const unsigned short* sA = lds + (t & 3) * SLOT;
        const unsigned short* sB = sA + 8192;
        unsigned short* ns = lds + ((t + 3) & 3) * SLOT;

        if (t + 3 < NTK) { STAGE_A(0, ns); STAGE_A(1, ns); STAGE_B(0, ns); STAGE_B(1, ns); }

        // one scheduling region: compiler pipelines ds_read -> MFMA per-fragment
        bf16x8 b00 = RDB32(0, kf0), b01 = RDB32(0, kf1);
        bf16x8 b10 = RDB32(1, kf0), b11 = RDB32(1, kf1);
        __builtin_amdgcn_s_setprio(1);
        MMROW(0); MMROW(1); MMROW(2); MMROW(3);
        __builtin_amdgcn_s_setprio(0);

        // tile boundary: counted wait (tile t+1 landed; t+2,t+3 in flight)
        if (t <= NTK - 4)      asm volatile("s_waitcnt vmcnt(8)" ::: "memory");
        else if (t == NTK - 3) asm volatile("s_waitcnt vmcnt(4)" ::: "memory");
        else                   asm volatile("s_waitcnt vmcnt(0)" ::: "memory");
        __builtin_amdgcn_s_barrier();
    }

    // epilogue: 32x32 C/D layout col = lane&31, row = (r&3)+8*(r>>2)+4*l5
    const int row0 = m0 + wr * 128 + 4 * l5;
    const int col0 = n0 + wc * 64 + l31;
    if (mode) {
#pragma unroll
        for (int mi = 0; mi < 4; ++mi)
#pragma unroll
            for (int ni = 0; ni < 2; ++ni)
#pragma unroll
                for (int r = 0; r < 16; ++r)
                    atomicAdd(&C[(size_t)(row0 + mi * 32 + (r & 3) + 8 * (r >> 2)) * OUT_F
                                 + (col0 + ni * 32)], acc[mi][ni][r]);
    } else {
        float* dst = kb ? P : C;
#pragma unroll
        for (int mi = 0; mi < 4; ++mi)
#pragma unroll
            for (int ni = 0; ni < 2; ++ni)
#pragma unroll
                for (int r = 0; r < 16; ++r)
                    dst[(size_t)(row0 + mi * 32 + (r & 3) + 8 * (r >> 2)) * OUT_F
                        + (col0 + ni * 32)] = acc[mi][ni][r];
    }
}

// ---------------------------------------------------------------------------
// Kernel 4: C += P (K-split reduction), float4.
// ---------------------------------------------------------------------------
__global__ void add_kernel(float* __restrict__ C, const float* __restrict__ P) {
    int i = blockIdx.x * blockDim.x + threadIdx.x;
    if (i >= BATCH * OUT_F / 4) return;
    f32x4* c4 = (f32x4*)C;
    const f32x4* p4 = (const f32x4*)P;
    c4[i] = c4[i] + p4[i];
}

// ---------------------------------------------------------------------------
extern "C" void kernel_launch(void* const* d_in, const int* in_sizes, int n_in,
                              void* d_out, int out_size, void* d_ws, size_t ws_size,
                              hipStream_t stream) {
    const float* x             = (const float*)d_in[0];
    const float* base_weight   = (const float*)d_in[1];
    const float* spline_weight = (const float*)d_in[2];
    const float* spline_scaler = (const float*)d_in[3];
    float* out = (float*)d_out;

    const size_t wbytes = (size_t)OUT_F * KDIM * 2;      // 18.9 MB
    const size_t abytes = (size_t)BATCH * KDIM * 2;      // 151 MB
    const size_t pbytes = (size_t)BATCH * OUT_F * 4;     // 33.5 MB
    unsigned short* Wc   = (unsigned short*)d_ws;
    unsigned short* Abuf = (unsigned short*)((char*)d_ws + wbytes);
    float*          P    = (float*)((char*)d_ws + wbytes + abytes);

    const int mode = (ws_size >= wbytes + abytes + pbytes) ? 0 : 1;
    if (mode == 1)
        hipMemsetAsync(d_out, 0, pbytes, stream);        // atomic fallback needs zeroed C

    wgt_kernel<<<(OUT_F * IN_F) / 256, 256, 0, stream>>>(
        base_weight, spline_weight, spline_scaler, Wc);
    act_kernel<<<(BATCH * 128) / 256, 256, 0, stream>>>(x, Abuf);

    gemm_ring<<<256, 512, 0, stream>>>(Abuf, Wc, out, P, mode);

    if (mode == 0)
        add_kernel<<<(BATCH * OUT_F / 4 + 255) / 256, 256, 0, stream>>>(out, P);
}